// Round 6
// baseline (587.736 us; speedup 1.0000x reference)
//
#include <hip/hip_runtime.h>
#include <cstdint>
#include <cstddef>

// Problem constants: N=4, C=D=256, H=W=64, L=4096
#define NB 4
#define CH 256
#define LL 4096

typedef unsigned short u16;
typedef unsigned int u32;
typedef unsigned char u8;
typedef __attribute__((ext_vector_type(8))) short bf16x8;
typedef __attribute__((ext_vector_type(4))) float f32x4;

#define GPTR(p) ((const __attribute__((address_space(1))) u32*)(p))
#define LPTR(p) ((__attribute__((address_space(3))) u32*)(p))

__device__ __forceinline__ float blo(u32 x) { return __uint_as_float(x << 16); }
__device__ __forceinline__ float bhi(u32 x) { return __uint_as_float(x & 0xffff0000u); }
__device__ __forceinline__ float b2f(u16 h) { return __uint_as_float(((u32)h) << 16); }
__device__ __forceinline__ u16 f2b(float f) {
    u32 u = __float_as_uint(f);
    u32 r = (u + 0x7fffu + ((u >> 16) & 1u)) >> 16;  // RNE
    return (u16)r;
}
__device__ __forceinline__ u32 pack2(float a, float b) {
    return (u32)f2b(a) | ((u32)f2b(b) << 16);
}

// ---------------------------------------------------------------------------
// Kernel P: fused castw + tcast (R16): independent prep work, one launch.
// ids [0,1024): tcast 64x64 tile; ids [1024,1280): castw + stats zero.
// Bodies byte-identical to R14's separate kernels; blockIdx decode only.
// ---------------------------------------------------------------------------
__global__ __launch_bounds__(256) void prep_kernel(
    const float* __restrict__ x, const float* __restrict__ Wq,
    const float* __restrict__ Wk, const float* __restrict__ Wv,
    const float* __restrict__ Wo, u16* __restrict__ Wb,
    float* __restrict__ stats, u16* __restrict__ xT) {
    const int id = blockIdx.x;
    const int tid = threadIdx.x;
    __shared__ u16 t[64][72];
    if (id < 1024) {
        // ---- tcast: x[n][c][l] f32 -> xT[n][l][c] bf16 ----
        const int n = id >> 8;
        const int c0 = ((id >> 6) & 3) * 64, l0 = (id & 63) * 64;
        const float* xs = x + (size_t)n * CH * LL;
        const int lq = (tid & 15) * 4, cc = tid >> 4;
#pragma unroll
        for (int p = 0; p < 4; ++p) {
            int c = cc + p * 16;
            float4 v = *(const float4*)&xs[(size_t)(c0 + c) * LL + l0 + lq];
            t[lq + 0][c] = f2b(v.x);
            t[lq + 1][c] = f2b(v.y);
            t[lq + 2][c] = f2b(v.z);
            t[lq + 3][c] = f2b(v.w);
        }
        __syncthreads();
        u16* xo = xT + (size_t)n * LL * CH;
        const int l = tid >> 2, c8 = (tid & 3) * 16;
#pragma unroll
        for (int h = 0; h < 2; ++h) {
            uint4 vv = *(uint4*)&t[l][c8 + h * 8];
            *(uint4*)&xo[(size_t)(l0 + l) * CH + c0 + c8 + h * 8] = vv;
        }
    } else {
        // ---- castw: weights f32 -> bf16 Wb[mat][d][c]; zero BN stats ----
        const int j = id - 1024;
        const int i = (j & 63) * 256 + tid;
        const int m = j >> 6;
        if (m == 0 && (j & 63) < 2) stats[i] = 0.0f;
        const float* src = (m == 0) ? Wq : (m == 1) ? Wk : (m == 2) ? Wv : Wo;
        float4 v = ((const float4*)src)[i];
        uint2 o;
        o.x = pack2(v.x, v.y);
        o.y = pack2(v.z, v.w);
        ((uint2*)(Wb + m * 65536))[i] = o;
    }
}

// ---------------------------------------------------------------------------
// Kernel 1: fused projqk + projv (R16): both 2-blocks/CU 64KB-LDS MFMA GEMMs
// reading xT+Wb; one 1536-block launch fills the machine (vs 1024+512 with a
// serialization gap and ragged tails). Bodies identical to R14.
// ids [0,1024): q/k projection; ids [1024,1536): v projection.
// ---------------------------------------------------------------------------
__global__ __launch_bounds__(256, 2) void proj_kernel(
    const u16* __restrict__ xT, const u16* __restrict__ Wb,
    u16* __restrict__ q, u16* __restrict__ k, u16* __restrict__ vT) {
    const int id = blockIdx.x;
    const int tid = threadIdx.x;
    const int w = tid >> 6, lane = tid & 63;
    const int lhi = lane >> 4, llo = lane & 15;

    __shared__ __align__(16) u16 Bs[128 * 256];  // 64 KB, chunk-XOR swizzled

    if (id < 1024) {
        // ---- projqk ----
        const int n = id >> 8;
        const int yy = (id >> 6) & 3;
        const int dhalf = yy & 1, mat = yy >> 1;
        const int l0 = (id & 63) * 64;
        const int d0 = dhalf * 128;

        const u16* xn = xT + (size_t)n * LL * CH;
        const u16* Wm = Wb + mat * 65536 + (size_t)d0 * CH;

#pragma unroll
        for (int i = 0; i < 16; ++i) {
            int s = i * 256 + tid;
            int r = s >> 5, c = s & 31;
            __builtin_amdgcn_global_load_lds(GPTR(Wm + r * CH + (c ^ (r & 31)) * 8),
                                             LPTR((char*)Bs + i * 4096 + w * 1024),
                                             16, 0, 0);
        }

        bf16x8 af[8];
        const u16* abase = xn + (size_t)(l0 + w * 16 + llo) * CH + lhi * 8;
#pragma unroll
        for (int ks = 0; ks < 8; ++ks) af[ks] = *(const bf16x8*)(abase + ks * 32);

        f32x4 acc[8];
#pragma unroll
        for (int t = 0; t < 8; ++t) acc[t] = (f32x4){0.f, 0.f, 0.f, 0.f};

        __syncthreads();

#pragma unroll
        for (int ks = 0; ks < 8; ++ks) {
#pragma unroll
            for (int ct = 0; ct < 8; ++ct) {
                const int rr = ct * 16 + llo;
                bf16x8 bf = *(const bf16x8*)(Bs + rr * CH +
                                             ((ks * 4 + lhi) ^ (rr & 31)) * 8);
                acc[ct] = __builtin_amdgcn_mfma_f32_16x16x32_bf16(af[ks], bf, acc[ct], 0, 0, 0);
            }
        }

        u16* o = (mat ? k : q) + (size_t)n * LL * CH;
#pragma unroll
        for (int r = 0; r < 4; ++r) {
            int lr = l0 + w * 16 + lhi * 4 + r;
#pragma unroll
            for (int ct = 0; ct < 8; ++ct)
                o[(size_t)lr * CH + d0 + ct * 16 + llo] = f2b(acc[ct][r]);
        }
    } else {
        // ---- projv ----
        const int j = id - 1024;
        const int n = j >> 7;
        const int d0 = ((j >> 5) & 3) * 64;
        const int l0 = (j & 31) * 128;

        const u16* xn = xT + (size_t)n * LL * CH + (size_t)l0 * CH;
        const u16* Wm = Wb + 2 * 65536;

#pragma unroll
        for (int i = 0; i < 16; ++i) {
            int s = i * 256 + tid;
            int r = s >> 5, c = s & 31;
            __builtin_amdgcn_global_load_lds(GPTR(xn + r * CH + (c ^ (r & 31)) * 8),
                                             LPTR((char*)Bs + i * 4096 + w * 1024),
                                             16, 0, 0);
        }

        bf16x8 af[8];
        const u16* abase = Wm + (size_t)(d0 + w * 16 + llo) * CH + lhi * 8;
#pragma unroll
        for (int ks = 0; ks < 8; ++ks) af[ks] = *(const bf16x8*)(abase + ks * 32);

        f32x4 acc[8];
#pragma unroll
        for (int t = 0; t < 8; ++t) acc[t] = (f32x4){0.f, 0.f, 0.f, 0.f};

        __syncthreads();

#pragma unroll
        for (int ks = 0; ks < 8; ++ks) {
#pragma unroll
            for (int ct = 0; ct < 8; ++ct) {
                const int rr = ct * 16 + llo;
                bf16x8 bf = *(const bf16x8*)(Bs + rr * CH +
                                             ((ks * 4 + lhi) ^ (rr & 31)) * 8);
                acc[ct] = __builtin_amdgcn_mfma_f32_16x16x32_bf16(af[ks], bf, acc[ct], 0, 0, 0);
            }
        }

        u16* o = vT + (size_t)n * CH * LL;
#pragma unroll
        for (int r = 0; r < 4; ++r) {
            int dr = d0 + w * 16 + lhi * 4 + r;
#pragma unroll
            for (int ct = 0; ct < 8; ++ct)
                o[(size_t)dr * LL + l0 + ct * 16 + llo] = f2b(acc[ct][r]);
        }
    }
}

// ---------------------------------------------------------------------------
// Kernel 2: bf16 flash attention (R16): R14 compute order (proven 90 us,
// R15's explicit PV-pipeline regressed -12% and was reverted), with LDS cut
// 64->48 KB for 3 blocks/CU (8->12 waves/CU). R14 audit: no pipe saturated
// (MFMA 30%, LDS ~46%, VALU 24%) => serial-chain latency at 25% occupancy is
// the wall; TLP is the lever (Guideline 1). K stays double-buffered (read at
// iter start, needs full-iter prefetch cover). V single-buffered: V is read
// LAST per iter, so V(it+1) issues after a raw s_barrier (all PV reads done
// -- guaranteed: MFMAs consumed the ds_read data before the barrier) and
// drains at the next __syncthreads' per-wave vmcnt(0) before any use.
// LDS 49152: K[2][32][256] @0/16384 | V[256][32] @32768. Math identical.
// ---------------------------------------------------------------------------
__global__ __launch_bounds__(256, 3) void fattn_kernel(
    const u16* __restrict__ q, const u16* __restrict__ k,
    const u16* __restrict__ vT, u16* __restrict__ Op, float* __restrict__ l_s,
    int iters) {
    const int n = blockIdx.y;
    const int s_id = blockIdx.z;
    const int l0 = blockIdx.x * 128;
    const int m_base = s_id * iters * 32;
    const int tid = threadIdx.x;
    const int w = tid >> 6;
    const int lane = tid & 63;
    const int lhi = lane >> 4, llo = lane & 15;

    __shared__ __align__(16) char smem[49152];
    // K buffers @ 0 / 16384 ; V buffer @ 32768

    bf16x8 qf[2][8];
    {
        const u16* base = q + (size_t)(n * LL + l0 + w * 32 + llo) * CH + lhi * 8;
#pragma unroll
        for (int t = 0; t < 2; ++t)
#pragma unroll
            for (int ks = 0; ks < 8; ++ks)
                qf[t][ks] = *(const bf16x8*)(base + t * 16 * CH + ks * 32);
    }

    const u16* kg = k + (size_t)n * LL * CH;
    const u16* vg = vT + (size_t)n * CH * LL;

    int okK[4], okV[4];
#pragma unroll
    for (int i = 0; i < 4; ++i) {
        int s = i * 256 + tid;
        int rK = s >> 5;
        int cK = (s & 31) ^ rK;
        okK[i] = rK * CH + cK * 8;
        int dV = s >> 2;
        int cV = (s & 3) ^ ((dV & 3) ^ ((dV >> 2) & 3));
        okV[i] = dV * LL + cV * 8;
    }

    f32x4 oacc[2][16];
#pragma unroll
    for (int t = 0; t < 2; ++t)
#pragma unroll
        for (int ct = 0; ct < 16; ++ct) oacc[t][ct] = (f32x4){0.f, 0.f, 0.f, 0.f};
    float lrun[2] = {0.f, 0.f};

    const float C1 = 0.09016844005556021f;  // (1/16) * log2(e)
    const int posV = (lhi ^ ((llo & 3) ^ (llo >> 2))) * 8;
    const int idxA = (llo + 32 * (lhi & 1)) * 4;
    const int idxB = idxA + 64;
    const bool selLo = (lhi < 2);

    // ---- prologue: issue K tile 0 and V tile 0 ----
    {
        const u16* kg2 = kg + (size_t)m_base * CH;
        const u16* vg2 = vg + m_base;
#pragma unroll
        for (int i = 0; i < 4; ++i) {
            __builtin_amdgcn_global_load_lds(GPTR(kg2 + okK[i]),
                                             LPTR(smem + i * 4096 + w * 1024), 16, 0, 0);
            __builtin_amdgcn_global_load_lds(GPTR(vg2 + okV[i]),
                                             LPTR(smem + 32768 + i * 4096 + w * 1024),
                                             16, 0, 0);
        }
    }

    for (int it = 0; it < iters; ++it) {
        __syncthreads();  // per-wave vmcnt(0): K(it) and V(it) resident
        // issue K(it+1) into the other K buffer (nobody reads it this iter)
        if (it + 1 < iters) {
            const u16* kg2 = kg + (size_t)(m_base + (it + 1) * 32) * CH;
            char* Kb = smem + ((it + 1) & 1) * 16384;
#pragma unroll
            for (int i = 0; i < 4; ++i) {
                __builtin_amdgcn_global_load_lds(GPTR(kg2 + okK[i]),
                                                 LPTR(Kb + i * 4096 + w * 1024), 16, 0, 0);
            }
        }
        const u16* Kl = (const u16*)(smem + (it & 1) * 16384);
        const u16* Vl = (const u16*)(smem + 32768);

        // ---- QK^T (swapped): lane holds q-row llo, k-cols kt*16+lhi*4+r ----
        f32x4 s00 = (f32x4){0.f, 0.f, 0.f, 0.f};
        f32x4 s01 = (f32x4){0.f, 0.f, 0.f, 0.f};
        f32x4 s10 = (f32x4){0.f, 0.f, 0.f, 0.f};
        f32x4 s11 = (f32x4){0.f, 0.f, 0.f, 0.f};
#pragma unroll
        for (int ks = 0; ks < 8; ++ks) {
            const int cq = ks * 4 + lhi;
            bf16x8 b0 = *(const bf16x8*)(Kl + llo * 256 + (cq ^ llo) * 8);
            bf16x8 b1 = *(const bf16x8*)(Kl + (llo + 16) * 256 + (cq ^ (llo + 16)) * 8);
            s00 = __builtin_amdgcn_mfma_f32_16x16x32_bf16(b0, qf[0][ks], s00, 0, 0, 0);
            s10 = __builtin_amdgcn_mfma_f32_16x16x32_bf16(b0, qf[1][ks], s10, 0, 0, 0);
            s01 = __builtin_amdgcn_mfma_f32_16x16x32_bf16(b1, qf[0][ks], s01, 0, 0, 0);
            s11 = __builtin_amdgcn_mfma_f32_16x16x32_bf16(b1, qf[1][ks], s11, 0, 0, 0);
        }

        // ---- softmax: p = exp2(s*C1); pack pairs; gather A-frags ----
        bf16x8 pa[2];
#pragma unroll
        for (int qt = 0; qt < 2; ++qt) {
            f32x4 sa = qt ? s10 : s00;   // kt = 0
            f32x4 sb = qt ? s11 : s01;   // kt = 1
            float pA0 = __builtin_amdgcn_exp2f(sa[0] * C1);
            float pA1 = __builtin_amdgcn_exp2f(sa[1] * C1);
            float pA2 = __builtin_amdgcn_exp2f(sa[2] * C1);
            float pA3 = __builtin_amdgcn_exp2f(sa[3] * C1);
            float pB0 = __builtin_amdgcn_exp2f(sb[0] * C1);
            float pB1 = __builtin_amdgcn_exp2f(sb[1] * C1);
            float pB2 = __builtin_amdgcn_exp2f(sb[2] * C1);
            float pB3 = __builtin_amdgcn_exp2f(sb[3] * C1);
            lrun[qt] += ((pA0 + pA1) + (pA2 + pA3)) + ((pB0 + pB1) + (pB2 + pB3));
            u32 w0, w1, w2, w3;
            asm("v_cvt_pk_bf16_f32 %0, %1, %2" : "=v"(w0) : "v"(pA0), "v"(pA1));
            asm("v_cvt_pk_bf16_f32 %0, %1, %2" : "=v"(w1) : "v"(pA2), "v"(pA3));
            asm("v_cvt_pk_bf16_f32 %0, %1, %2" : "=v"(w2) : "v"(pB0), "v"(pB1));
            asm("v_cvt_pk_bf16_f32 %0, %1, %2" : "=v"(w3) : "v"(pB2), "v"(pB3));
            int t0 = __builtin_amdgcn_ds_bpermute(idxA, (int)w0);
            int t2 = __builtin_amdgcn_ds_bpermute(idxA, (int)w2);
            int u0 = __builtin_amdgcn_ds_bpermute(idxA, (int)w1);
            int u2 = __builtin_amdgcn_ds_bpermute(idxA, (int)w3);
            int v0 = __builtin_amdgcn_ds_bpermute(idxB, (int)w0);
            int v2 = __builtin_amdgcn_ds_bpermute(idxB, (int)w2);
            int x0 = __builtin_amdgcn_ds_bpermute(idxB, (int)w1);
            int x2 = __builtin_amdgcn_ds_bpermute(idxB, (int)w3);
            union { u32 u[4]; bf16x8 v; } pk;
            pk.u[0] = selLo ? (u32)t0 : (u32)t2;
            pk.u[1] = selLo ? (u32)u0 : (u32)u2;
            pk.u[2] = selLo ? (u32)v0 : (u32)v2;
            pk.u[3] = selLo ? (u32)x0 : (u32)x2;
            pa[qt] = pk.v;
        }

        // ---- PV (reads single V buffer) ----
#pragma unroll
        for (int ct = 0; ct < 16; ++ct) {
            bf16x8 vf = *(const bf16x8*)(Vl + (ct * 16 + llo) * 32 + posV);
            oacc[0][ct] = __builtin_amdgcn_mfma_f32_16x16x32_bf16(pa[0], vf, oacc[0][ct], 0, 0, 0);
            oacc[1][ct] = __builtin_amdgcn_mfma_f32_16x16x32_bf16(pa[1], vf, oacc[1][ct], 0, 0, 0);
        }

        // ---- all waves done reading V(it) -> overwrite with V(it+1) ----
        if (it + 1 < iters) {
            __builtin_amdgcn_s_barrier();
            const u16* vg2 = vg + m_base + (it + 1) * 32;
#pragma unroll
            for (int i = 0; i < 4; ++i) {
                __builtin_amdgcn_global_load_lds(GPTR(vg2 + okV[i]),
                                                 LPTR(smem + 32768 + i * 4096 + w * 1024),
                                                 16, 0, 0);
            }
        }
    }

    u16* ap = Op + (size_t)((s_id * NB + n) * (size_t)LL + l0 + w * 32) * CH;
    float* lp = l_s + (size_t)s_id * NB * LL + (size_t)n * LL + l0 + w * 32;
#pragma unroll
    for (int t = 0; t < 2; ++t) {
        float ls = lrun[t];
        ls += __shfl_xor(ls, 16);
        ls += __shfl_xor(ls, 32);
        if (lhi == 0) lp[t * 16 + llo] = ls;
#pragma unroll
        for (int r = 0; r < 4; ++r) {
            int lrow = t * 16 + lhi * 4 + r;
#pragma unroll
            for (int ct = 0; ct < 16; ++ct) {
                ap[(size_t)lrow * CH + ct * 16 + llo] = f2b(oacc[t][ct][r]);
            }
        }
    }
}

// ---------------------------------------------------------------------------
// Kernel 2c: merge splits: att[i] = (sum_s Op[s][i]) / (sum_s l_s[s][row])
// ---------------------------------------------------------------------------
__global__ __launch_bounds__(256) void merge_kernel(
    const u16* __restrict__ Op, const float* __restrict__ l_s,
    u16* __restrict__ att, int S) {
    const size_t t8 = (size_t)blockIdx.x * 256 + threadIdx.x;
    const size_t flat = t8 * 8;
    const size_t row = flat >> 8;
    float lsum = 0.0f;
    for (int s = 0; s < S; ++s) lsum += l_s[(size_t)s * NB * LL + row];
    const float inv = 1.0f / lsum;
    float acc[8];
#pragma unroll
    for (int j = 0; j < 8; ++j) acc[j] = 0.0f;
    for (int s = 0; s < S; ++s) {
        uint4 raw = *(const uint4*)(Op + (size_t)s * NB * LL * CH + flat);
        acc[0] += blo(raw.x); acc[1] += bhi(raw.x);
        acc[2] += blo(raw.y); acc[3] += bhi(raw.y);
        acc[4] += blo(raw.z); acc[5] += bhi(raw.z);
        acc[6] += blo(raw.w); acc[7] += bhi(raw.w);
    }
    uint4 o;
    o.x = pack2(acc[0] * inv, acc[1] * inv);
    o.y = pack2(acc[2] * inv, acc[3] * inv);
    o.z = pack2(acc[4] * inv, acc[5] * inv);
    o.w = pack2(acc[6] * inv, acc[7] * inv);
    *(uint4*)(att + flat) = o;
}

// ---------------------------------------------------------------------------
// Kernel 3: output projection via MFMA + fused BN partial sums. y bf16.
// B = att l-tile staged in LDS (R14 template).
// ---------------------------------------------------------------------------
__global__ __launch_bounds__(256, 2) void outm_kernel(
    const u16* __restrict__ Wb, const u16* __restrict__ att,
    u16* __restrict__ y, float* __restrict__ stats) {
    const int n = blockIdx.z;
    const int o0 = blockIdx.y * 64;
    const int l0 = blockIdx.x * 128;
    const int tid = threadIdx.x;
    const int w = tid >> 6, lane = tid & 63;
    const int lhi = lane >> 4, llo = lane & 15;

    __shared__ __align__(16) u16 Bs[128 * 256];  // 64 KB

    const u16* an = att + (size_t)n * LL * CH + (size_t)l0 * CH;
    const u16* Wm = Wb + 3 * 65536;

#pragma unroll
    for (int i = 0; i < 16; ++i) {
        int s = i * 256 + tid;
        int r = s >> 5, c = s & 31;
        __builtin_amdgcn_global_load_lds(GPTR(an + r * CH + (c ^ (r & 31)) * 8),
                                         LPTR((char*)Bs + i * 4096 + w * 1024),
                                         16, 0, 0);
    }

    bf16x8 af[8];
    const u16* abase = Wm + (size_t)(o0 + w * 16 + llo) * CH + lhi * 8;
#pragma unroll
    for (int ks = 0; ks < 8; ++ks) af[ks] = *(const bf16x8*)(abase + ks * 32);

    f32x4 acc[8];
#pragma unroll
    for (int t = 0; t < 8; ++t) acc[t] = (f32x4){0.f, 0.f, 0.f, 0.f};

    __syncthreads();

#pragma unroll
    for (int ks = 0; ks < 8; ++ks) {
#pragma unroll
        for (int ct = 0; ct < 8; ++ct) {
            const int rr = ct * 16 + llo;
            bf16x8 bf = *(const bf16x8*)(Bs + rr * CH +
                                         ((ks * 4 + lhi) ^ (rr & 31)) * 8);
            acc[ct] = __builtin_amdgcn_mfma_f32_16x16x32_bf16(af[ks], bf, acc[ct], 0, 0, 0);
        }
    }

    u16* yn = y + (size_t)n * CH * LL;
#pragma unroll
    for (int r = 0; r < 4; ++r) {
        const int orow = o0 + w * 16 + lhi * 4 + r;
        float ts = 0.0f, tq = 0.0f;
#pragma unroll
        for (int ct = 0; ct < 8; ++ct) {
            float vv = acc[ct][r];
            yn[(size_t)orow * LL + l0 + ct * 16 + llo] = f2b(vv);
            ts += vv;
            tq += vv * vv;
        }
        ts += __shfl_xor(ts, 1); tq += __shfl_xor(tq, 1);
        ts += __shfl_xor(ts, 2); tq += __shfl_xor(tq, 2);
        ts += __shfl_xor(ts, 4); tq += __shfl_xor(tq, 4);
        ts += __shfl_xor(ts, 8); tq += __shfl_xor(tq, 8);
        if (llo == 0) {
            atomicAdd(&stats[orow], ts);
            atomicAdd(&stats[256 + orow], tq);
        }
    }
}

// ---------------------------------------------------------------------------
// Kernel 4: BN apply (batch stats, biased var) + residual. y read as bf16.
// ---------------------------------------------------------------------------
__global__ __launch_bounds__(256) void bn_kernel(
    const float* __restrict__ x, const u16* __restrict__ y,
    const float* __restrict__ stats, const float* __restrict__ gamma,
    const float* __restrict__ beta, float* __restrict__ out) {
    const int idx = blockIdx.x * 256 + threadIdx.x;  // per 4 elems
    const int base = idx * 4;
    const int c = (base >> 12) & 255;  // (base / L) % C
    const float cnt = 1.0f / 16384.0f; // N*L
    float mean = stats[c] * cnt;
    float var = stats[256 + c] * cnt - mean * mean;
    float rstd = rsqrtf(var + 1e-4f);
    float g = gamma[c] * rstd;
    float b = beta[c];
    uint2 yv = ((const uint2*)y)[idx];
    float4 xv = ((const float4*)x)[idx];
    float4 o;
    o.x = xv.x + (blo(yv.x) - mean) * g + b;
    o.y = xv.y + (bhi(yv.x) - mean) * g + b;
    o.z = xv.z + (blo(yv.y) - mean) * g + b;
    o.w = xv.w + (bhi(yv.y) - mean) * g + b;
    ((float4*)out)[idx] = o;
}

// ---------------------------------------------------------------------------
extern "C" void kernel_launch(void* const* d_in, const int* in_sizes, int n_in,
                              void* d_out, int out_size, void* d_ws, size_t ws_size,
                              hipStream_t stream) {
    const float* x = (const float*)d_in[0];
    const float* Wq = (const float*)d_in[1];
    const float* Wk = (const float*)d_in[2];
    const float* Wv = (const float*)d_in[3];
    const float* Wo = (const float*)d_in[4];
    const float* gamma = (const float*)d_in[5];
    const float* beta = (const float*)d_in[6];
    float* out = (float*)d_out;

    const size_t elems = (size_t)NB * LL * CH;  // 4,194,304

    // pick largest split count whose workspace fits (S=4 needs ~59.4 MB)
    int S = 1;
    for (int cand = 4; cand >= 2; cand >>= 1) {
        size_t need = elems * 2 * (size_t)(3 + cand) +
                      (size_t)cand * NB * LL * 4 + 524288 + 8192;
        if (ws_size >= need) { S = cand; break; }
    }
    const int iters = 128 / S;

    char* wsb = (char*)d_ws;
    u16* q = (u16*)wsb;                             // 8.39 MB (bf16)
    u16* k = q + elems;                             // 8.39 MB (bf16)
    u16* vT = k + elems;                            // 8.39 MB (bf16)
    u16* Op = vT + elems;                           // S * 8.39 MB (bf16)
    u16* xT = Op;                                   // overlay: dead before fattn
    float* l_s = (float*)(Op + (size_t)S * elems);  // S * 64 KB
    u16* Wb = (u16*)(l_s + (size_t)S * NB * LL);    // 512 KB
    float* stats = (float*)(Wb + 4 * 65536);        // 2 KB
    u16* att = q;   // overlay q (dead after fattn)
    u16* y = k;     // overlay k (dead after merge)

    prep_kernel<<<1280, 256, 0, stream>>>(x, Wq, Wk, Wv, Wo, Wb, stats, xT);
    proj_kernel<<<1536, 256, 0, stream>>>(xT, Wb, q, k, vT);
    fattn_kernel<<<dim3(LL / 128, NB, S), 256, 0, stream>>>(q, k, vT, Op, l_s, iters);
    merge_kernel<<<(int)(elems / 8 / 256), 256, 0, stream>>>(Op, l_s, att, S);
    outm_kernel<<<dim3(LL / 128, CH / 64, NB), 256, 0, stream>>>(Wb, att, y, stats);
    bn_kernel<<<(NB * CH * LL / 4) / 256, 256, 0, stream>>>(x, y, stats, gamma, beta, out);
}

// Round 7
// 203.732 us; speedup vs baseline: 2.8849x; 2.8849x over previous
//
#include <hip/hip_runtime.h>
#include <cstdint>
#include <cstddef>

// Problem constants: N=4, C=D=256, H=W=64, L=4096
#define NB 4
#define CH 256
#define LL 4096

typedef unsigned short u16;
typedef unsigned int u32;
typedef unsigned char u8;
typedef __attribute__((ext_vector_type(8))) short bf16x8;
typedef __attribute__((ext_vector_type(4))) float f32x4;

#define GPTR(p) ((const __attribute__((address_space(1))) u32*)(p))
#define LPTR(p) ((__attribute__((address_space(3))) u32*)(p))

__device__ __forceinline__ float blo(u32 x) { return __uint_as_float(x << 16); }
__device__ __forceinline__ float bhi(u32 x) { return __uint_as_float(x & 0xffff0000u); }
__device__ __forceinline__ float b2f(u16 h) { return __uint_as_float(((u32)h) << 16); }
__device__ __forceinline__ u16 f2b(float f) {
    u32 u = __float_as_uint(f);
    u32 r = (u + 0x7fffu + ((u >> 16) & 1u)) >> 16;  // RNE
    return (u16)r;
}
__device__ __forceinline__ u32 pack2(float a, float b) {
    return (u32)f2b(a) | ((u32)f2b(b) << 16);
}

// ---------------------------------------------------------------------------
// Kernel P: fused castw + tcast (R16, kept: non-fattn time 118->114 us).
// ids [0,1024): tcast 64x64 tile; ids [1024,1280): castw + stats zero.
// ---------------------------------------------------------------------------
__global__ __launch_bounds__(256) void prep_kernel(
    const float* __restrict__ x, const float* __restrict__ Wq,
    const float* __restrict__ Wk, const float* __restrict__ Wv,
    const float* __restrict__ Wo, u16* __restrict__ Wb,
    float* __restrict__ stats, u16* __restrict__ xT) {
    const int id = blockIdx.x;
    const int tid = threadIdx.x;
    __shared__ u16 t[64][72];
    if (id < 1024) {
        // ---- tcast: x[n][c][l] f32 -> xT[n][l][c] bf16 ----
        const int n = id >> 8;
        const int c0 = ((id >> 6) & 3) * 64, l0 = (id & 63) * 64;
        const float* xs = x + (size_t)n * CH * LL;
        const int lq = (tid & 15) * 4, cc = tid >> 4;
#pragma unroll
        for (int p = 0; p < 4; ++p) {
            int c = cc + p * 16;
            float4 v = *(const float4*)&xs[(size_t)(c0 + c) * LL + l0 + lq];
            t[lq + 0][c] = f2b(v.x);
            t[lq + 1][c] = f2b(v.y);
            t[lq + 2][c] = f2b(v.z);
            t[lq + 3][c] = f2b(v.w);
        }
        __syncthreads();
        u16* xo = xT + (size_t)n * LL * CH;
        const int l = tid >> 2, c8 = (tid & 3) * 16;
#pragma unroll
        for (int h = 0; h < 2; ++h) {
            uint4 vv = *(uint4*)&t[l][c8 + h * 8];
            *(uint4*)&xo[(size_t)(l0 + l) * CH + c0 + c8 + h * 8] = vv;
        }
    } else {
        // ---- castw: weights f32 -> bf16 Wb[mat][d][c]; zero BN stats ----
        const int j = id - 1024;
        const int i = (j & 63) * 256 + tid;
        const int m = j >> 6;
        if (m == 0 && (j & 63) < 2) stats[i] = 0.0f;
        const float* src = (m == 0) ? Wq : (m == 1) ? Wk : (m == 2) ? Wv : Wo;
        float4 v = ((const float4*)src)[i];
        uint2 o;
        o.x = pack2(v.x, v.y);
        o.y = pack2(v.z, v.w);
        ((uint2*)(Wb + m * 65536))[i] = o;
    }
}

// ---------------------------------------------------------------------------
// Kernel 1: fused projqk + projv (R16, kept). LDS-staged B-operand (R14
// template). ids [0,1024): q/k projection; ids [1024,1536): v projection.
// ---------------------------------------------------------------------------
__global__ __launch_bounds__(256, 2) void proj_kernel(
    const u16* __restrict__ xT, const u16* __restrict__ Wb,
    u16* __restrict__ q, u16* __restrict__ k, u16* __restrict__ vT) {
    const int id = blockIdx.x;
    const int tid = threadIdx.x;
    const int w = tid >> 6, lane = tid & 63;
    const int lhi = lane >> 4, llo = lane & 15;

    __shared__ __align__(16) u16 Bs[128 * 256];  // 64 KB, chunk-XOR swizzled

    if (id < 1024) {
        // ---- projqk ----
        const int n = id >> 8;
        const int yy = (id >> 6) & 3;
        const int dhalf = yy & 1, mat = yy >> 1;
        const int l0 = (id & 63) * 64;
        const int d0 = dhalf * 128;

        const u16* xn = xT + (size_t)n * LL * CH;
        const u16* Wm = Wb + mat * 65536 + (size_t)d0 * CH;

#pragma unroll
        for (int i = 0; i < 16; ++i) {
            int s = i * 256 + tid;
            int r = s >> 5, c = s & 31;
            __builtin_amdgcn_global_load_lds(GPTR(Wm + r * CH + (c ^ (r & 31)) * 8),
                                             LPTR((char*)Bs + i * 4096 + w * 1024),
                                             16, 0, 0);
        }

        bf16x8 af[8];
        const u16* abase = xn + (size_t)(l0 + w * 16 + llo) * CH + lhi * 8;
#pragma unroll
        for (int ks = 0; ks < 8; ++ks) af[ks] = *(const bf16x8*)(abase + ks * 32);

        f32x4 acc[8];
#pragma unroll
        for (int t = 0; t < 8; ++t) acc[t] = (f32x4){0.f, 0.f, 0.f, 0.f};

        __syncthreads();

#pragma unroll
        for (int ks = 0; ks < 8; ++ks) {
#pragma unroll
            for (int ct = 0; ct < 8; ++ct) {
                const int rr = ct * 16 + llo;
                bf16x8 bf = *(const bf16x8*)(Bs + rr * CH +
                                             ((ks * 4 + lhi) ^ (rr & 31)) * 8);
                acc[ct] = __builtin_amdgcn_mfma_f32_16x16x32_bf16(af[ks], bf, acc[ct], 0, 0, 0);
            }
        }

        u16* o = (mat ? k : q) + (size_t)n * LL * CH;
#pragma unroll
        for (int r = 0; r < 4; ++r) {
            int lr = l0 + w * 16 + lhi * 4 + r;
#pragma unroll
            for (int ct = 0; ct < 8; ++ct)
                o[(size_t)lr * CH + d0 + ct * 16 + llo] = f2b(acc[ct][r]);
        }
    } else {
        // ---- projv ----
        const int j = id - 1024;
        const int n = j >> 7;
        const int d0 = ((j >> 5) & 3) * 64;
        const int l0 = (j & 31) * 128;

        const u16* xn = xT + (size_t)n * LL * CH + (size_t)l0 * CH;
        const u16* Wm = Wb + 2 * 65536;

#pragma unroll
        for (int i = 0; i < 16; ++i) {
            int s = i * 256 + tid;
            int r = s >> 5, c = s & 31;
            __builtin_amdgcn_global_load_lds(GPTR(xn + r * CH + (c ^ (r & 31)) * 8),
                                             LPTR((char*)Bs + i * 4096 + w * 1024),
                                             16, 0, 0);
        }

        bf16x8 af[8];
        const u16* abase = Wm + (size_t)(d0 + w * 16 + llo) * CH + lhi * 8;
#pragma unroll
        for (int ks = 0; ks < 8; ++ks) af[ks] = *(const bf16x8*)(abase + ks * 32);

        f32x4 acc[8];
#pragma unroll
        for (int t = 0; t < 8; ++t) acc[t] = (f32x4){0.f, 0.f, 0.f, 0.f};

        __syncthreads();

#pragma unroll
        for (int ks = 0; ks < 8; ++ks) {
#pragma unroll
            for (int ct = 0; ct < 8; ++ct) {
                const int rr = ct * 16 + llo;
                bf16x8 bf = *(const bf16x8*)(Bs + rr * CH +
                                             ((ks * 4 + lhi) ^ (rr & 31)) * 8);
                acc[ct] = __builtin_amdgcn_mfma_f32_16x16x32_bf16(af[ks], bf, acc[ct], 0, 0, 0);
            }
        }

        u16* o = vT + (size_t)n * CH * LL;
#pragma unroll
        for (int r = 0; r < 4; ++r) {
            int dr = d0 + w * 16 + lhi * 4 + r;
#pragma unroll
            for (int ct = 0; ct < 8; ++ct)
                o[(size_t)dr * LL + l0 + ct * 16 + llo] = f2b(acc[ct][r]);
        }
    }
}

// ---------------------------------------------------------------------------
// Kernel 2: bf16 flash attention (R17 = R14 EXACT REVERT + setprio probe).
// R6 post-mortem: __launch_bounds__(256,3) forced <=170 regs/wave vs ~250
// live (oacc 128 f32 + qf 64) -> accumulator SPILLED to scratch (VGPR 84,
// WRITE_SIZE 608 MB, 5x slower). fattn is register-capped at 2 waves/SIMD;
// occupancy is NOT a lever here. R15's explicit PV pipeline also regressed
// (-12%); R14's compiler-scheduled order is the proven optimum (90 us,
// MfmaUtil 32). Only addition: s_setprio(1) around MFMA clusters (m191:
// +4-7% on attn structures; 2 independent blocks/CU give phase diversity).
// LDS 65536: K[2][32][256] | V[2][256][32] (chunk-XOR swizzles). 2 blk/CU.
// ---------------------------------------------------------------------------
__global__ __launch_bounds__(256, 2) void fattn_kernel(
    const u16* __restrict__ q, const u16* __restrict__ k,
    const u16* __restrict__ vT, u16* __restrict__ Op, float* __restrict__ l_s,
    int iters) {
    const int n = blockIdx.y;
    const int s_id = blockIdx.z;
    const int l0 = blockIdx.x * 128;
    const int m_base = s_id * iters * 32;
    const int tid = threadIdx.x;
    const int w = tid >> 6;
    const int lane = tid & 63;
    const int lhi = lane >> 4, llo = lane & 15;

    __shared__ __align__(16) char smem[65536];
    // K buffers @ 0 / 16384 ; V buffers @ 32768 / 49152

    bf16x8 qf[2][8];
    {
        const u16* base = q + (size_t)(n * LL + l0 + w * 32 + llo) * CH + lhi * 8;
#pragma unroll
        for (int t = 0; t < 2; ++t)
#pragma unroll
            for (int ks = 0; ks < 8; ++ks)
                qf[t][ks] = *(const bf16x8*)(base + t * 16 * CH + ks * 32);
    }

    const u16* kg = k + (size_t)n * LL * CH;
    const u16* vg = vT + (size_t)n * CH * LL;

    int okK[4], okV[4];
#pragma unroll
    for (int i = 0; i < 4; ++i) {
        int s = i * 256 + tid;
        int rK = s >> 5;
        int cK = (s & 31) ^ rK;
        okK[i] = rK * CH + cK * 8;
        int dV = s >> 2;
        int cV = (s & 3) ^ ((dV & 3) ^ ((dV >> 2) & 3));
        okV[i] = dV * LL + cV * 8;
    }

    f32x4 oacc[2][16];
#pragma unroll
    for (int t = 0; t < 2; ++t)
#pragma unroll
        for (int ct = 0; ct < 16; ++ct) oacc[t][ct] = (f32x4){0.f, 0.f, 0.f, 0.f};
    float lrun[2] = {0.f, 0.f};

    const float C1 = 0.09016844005556021f;  // (1/16) * log2(e)
    const int posV = (lhi ^ ((llo & 3) ^ (llo >> 2))) * 8;
    const int idxA = (llo + 32 * (lhi & 1)) * 4;
    const int idxB = idxA + 64;
    const bool selLo = (lhi < 2);

    {
        const u16* kg2 = kg + (size_t)m_base * CH;
        const u16* vg2 = vg + m_base;
#pragma unroll
        for (int i = 0; i < 4; ++i) {
            __builtin_amdgcn_global_load_lds(GPTR(kg2 + okK[i]),
                                             LPTR(smem + i * 4096 + w * 1024), 16, 0, 0);
            __builtin_amdgcn_global_load_lds(GPTR(vg2 + okV[i]),
                                             LPTR(smem + 32768 + i * 4096 + w * 1024),
                                             16, 0, 0);
        }
    }

    for (int it = 0; it < iters; ++it) {
        __syncthreads();
        if (it + 1 < iters) {
            const int m1 = m_base + (it + 1) * 32;
            const u16* kg2 = kg + (size_t)m1 * CH;
            const u16* vg2 = vg + m1;
            char* Kb = smem + ((it + 1) & 1) * 16384;
            char* Vb = smem + 32768 + ((it + 1) & 1) * 16384;
#pragma unroll
            for (int i = 0; i < 4; ++i) {
                __builtin_amdgcn_global_load_lds(GPTR(kg2 + okK[i]),
                                                 LPTR(Kb + i * 4096 + w * 1024), 16, 0, 0);
                __builtin_amdgcn_global_load_lds(GPTR(vg2 + okV[i]),
                                                 LPTR(Vb + i * 4096 + w * 1024), 16, 0, 0);
            }
        }
        const u16* Kl = (const u16*)(smem + (it & 1) * 16384);
        const u16* Vl = (const u16*)(smem + 32768 + (it & 1) * 16384);

        // ---- QK^T (swapped): lane holds q-row llo, k-cols kt*16+lhi*4+r ----
        f32x4 s00 = (f32x4){0.f, 0.f, 0.f, 0.f};
        f32x4 s01 = (f32x4){0.f, 0.f, 0.f, 0.f};
        f32x4 s10 = (f32x4){0.f, 0.f, 0.f, 0.f};
        f32x4 s11 = (f32x4){0.f, 0.f, 0.f, 0.f};
        __builtin_amdgcn_s_setprio(1);
#pragma unroll
        for (int ks = 0; ks < 8; ++ks) {
            const int cq = ks * 4 + lhi;
            bf16x8 b0 = *(const bf16x8*)(Kl + llo * 256 + (cq ^ llo) * 8);
            bf16x8 b1 = *(const bf16x8*)(Kl + (llo + 16) * 256 + (cq ^ (llo + 16)) * 8);
            s00 = __builtin_amdgcn_mfma_f32_16x16x32_bf16(b0, qf[0][ks], s00, 0, 0, 0);
            s10 = __builtin_amdgcn_mfma_f32_16x16x32_bf16(b0, qf[1][ks], s10, 0, 0, 0);
            s01 = __builtin_amdgcn_mfma_f32_16x16x32_bf16(b1, qf[0][ks], s01, 0, 0, 0);
            s11 = __builtin_amdgcn_mfma_f32_16x16x32_bf16(b1, qf[1][ks], s11, 0, 0, 0);
        }
        __builtin_amdgcn_s_setprio(0);

        // ---- softmax: p = exp2(s*C1); pack pairs; gather A-frags ----
        bf16x8 pa[2];
#pragma unroll
        for (int qt = 0; qt < 2; ++qt) {
            f32x4 sa = qt ? s10 : s00;   // kt = 0
            f32x4 sb = qt ? s11 : s01;   // kt = 1
            float pA0 = __builtin_amdgcn_exp2f(sa[0] * C1);
            float pA1 = __builtin_amdgcn_exp2f(sa[1] * C1);
            float pA2 = __builtin_amdgcn_exp2f(sa[2] * C1);
            float pA3 = __builtin_amdgcn_exp2f(sa[3] * C1);
            float pB0 = __builtin_amdgcn_exp2f(sb[0] * C1);
            float pB1 = __builtin_amdgcn_exp2f(sb[1] * C1);
            float pB2 = __builtin_amdgcn_exp2f(sb[2] * C1);
            float pB3 = __builtin_amdgcn_exp2f(sb[3] * C1);
            lrun[qt] += ((pA0 + pA1) + (pA2 + pA3)) + ((pB0 + pB1) + (pB2 + pB3));
            u32 w0, w1, w2, w3;
            asm("v_cvt_pk_bf16_f32 %0, %1, %2" : "=v"(w0) : "v"(pA0), "v"(pA1));
            asm("v_cvt_pk_bf16_f32 %0, %1, %2" : "=v"(w1) : "v"(pA2), "v"(pA3));
            asm("v_cvt_pk_bf16_f32 %0, %1, %2" : "=v"(w2) : "v"(pB0), "v"(pB1));
            asm("v_cvt_pk_bf16_f32 %0, %1, %2" : "=v"(w3) : "v"(pB2), "v"(pB3));
            int t0 = __builtin_amdgcn_ds_bpermute(idxA, (int)w0);
            int t2 = __builtin_amdgcn_ds_bpermute(idxA, (int)w2);
            int u0 = __builtin_amdgcn_ds_bpermute(idxA, (int)w1);
            int u2 = __builtin_amdgcn_ds_bpermute(idxA, (int)w3);
            int v0 = __builtin_amdgcn_ds_bpermute(idxB, (int)w0);
            int v2 = __builtin_amdgcn_ds_bpermute(idxB, (int)w2);
            int x0 = __builtin_amdgcn_ds_bpermute(idxB, (int)w1);
            int x2 = __builtin_amdgcn_ds_bpermute(idxB, (int)w3);
            union { u32 u[4]; bf16x8 v; } pk;
            pk.u[0] = selLo ? (u32)t0 : (u32)t2;
            pk.u[1] = selLo ? (u32)u0 : (u32)u2;
            pk.u[2] = selLo ? (u32)v0 : (u32)v2;
            pk.u[3] = selLo ? (u32)x0 : (u32)x2;
            pa[qt] = pk.v;
        }

        // ---- PV ----
        __builtin_amdgcn_s_setprio(1);
#pragma unroll
        for (int ct = 0; ct < 16; ++ct) {
            bf16x8 vf = *(const bf16x8*)(Vl + (ct * 16 + llo) * 32 + posV);
            oacc[0][ct] = __builtin_amdgcn_mfma_f32_16x16x32_bf16(pa[0], vf, oacc[0][ct], 0, 0, 0);
            oacc[1][ct] = __builtin_amdgcn_mfma_f32_16x16x32_bf16(pa[1], vf, oacc[1][ct], 0, 0, 0);
        }
        __builtin_amdgcn_s_setprio(0);
    }

    u16* ap = Op + (size_t)((s_id * NB + n) * (size_t)LL + l0 + w * 32) * CH;
    float* lp = l_s + (size_t)s_id * NB * LL + (size_t)n * LL + l0 + w * 32;
#pragma unroll
    for (int t = 0; t < 2; ++t) {
        float ls = lrun[t];
        ls += __shfl_xor(ls, 16);
        ls += __shfl_xor(ls, 32);
        if (lhi == 0) lp[t * 16 + llo] = ls;
#pragma unroll
        for (int r = 0; r < 4; ++r) {
            int lrow = t * 16 + lhi * 4 + r;
#pragma unroll
            for (int ct = 0; ct < 16; ++ct) {
                ap[(size_t)lrow * CH + ct * 16 + llo] = f2b(oacc[t][ct][r]);
            }
        }
    }
}

// ---------------------------------------------------------------------------
// Kernel 2c: merge splits: att[i] = (sum_s Op[s][i]) / (sum_s l_s[s][row])
// ---------------------------------------------------------------------------
__global__ __launch_bounds__(256) void merge_kernel(
    const u16* __restrict__ Op, const float* __restrict__ l_s,
    u16* __restrict__ att, int S) {
    const size_t t8 = (size_t)blockIdx.x * 256 + threadIdx.x;
    const size_t flat = t8 * 8;
    const size_t row = flat >> 8;
    float lsum = 0.0f;
    for (int s = 0; s < S; ++s) lsum += l_s[(size_t)s * NB * LL + row];
    const float inv = 1.0f / lsum;
    float acc[8];
#pragma unroll
    for (int j = 0; j < 8; ++j) acc[j] = 0.0f;
    for (int s = 0; s < S; ++s) {
        uint4 raw = *(const uint4*)(Op + (size_t)s * NB * LL * CH + flat);
        acc[0] += blo(raw.x); acc[1] += bhi(raw.x);
        acc[2] += blo(raw.y); acc[3] += bhi(raw.y);
        acc[4] += blo(raw.z); acc[5] += bhi(raw.z);
        acc[6] += blo(raw.w); acc[7] += bhi(raw.w);
    }
    uint4 o;
    o.x = pack2(acc[0] * inv, acc[1] * inv);
    o.y = pack2(acc[2] * inv, acc[3] * inv);
    o.z = pack2(acc[4] * inv, acc[5] * inv);
    o.w = pack2(acc[6] * inv, acc[7] * inv);
    *(uint4*)(att + flat) = o;
}

// ---------------------------------------------------------------------------
// Kernel 3: output projection via MFMA + fused BN partial sums. y bf16.
// B = att l-tile staged in LDS (R14 template).
// ---------------------------------------------------------------------------
__global__ __launch_bounds__(256, 2) void outm_kernel(
    const u16* __restrict__ Wb, const u16* __restrict__ att,
    u16* __restrict__ y, float* __restrict__ stats) {
    const int n = blockIdx.z;
    const int o0 = blockIdx.y * 64;
    const int l0 = blockIdx.x * 128;
    const int tid = threadIdx.x;
    const int w = tid >> 6, lane = tid & 63;
    const int lhi = lane >> 4, llo = lane & 15;

    __shared__ __align__(16) u16 Bs[128 * 256];  // 64 KB

    const u16* an = att + (size_t)n * LL * CH + (size_t)l0 * CH;
    const u16* Wm = Wb + 3 * 65536;

#pragma unroll
    for (int i = 0; i < 16; ++i) {
        int s = i * 256 + tid;
        int r = s >> 5, c = s & 31;
        __builtin_amdgcn_global_load_lds(GPTR(an + r * CH + (c ^ (r & 31)) * 8),
                                         LPTR((char*)Bs + i * 4096 + w * 1024),
                                         16, 0, 0);
    }

    bf16x8 af[8];
    const u16* abase = Wm + (size_t)(o0 + w * 16 + llo) * CH + lhi * 8;
#pragma unroll
    for (int ks = 0; ks < 8; ++ks) af[ks] = *(const bf16x8*)(abase + ks * 32);

    f32x4 acc[8];
#pragma unroll
    for (int t = 0; t < 8; ++t) acc[t] = (f32x4){0.f, 0.f, 0.f, 0.f};

    __syncthreads();

#pragma unroll
    for (int ks = 0; ks < 8; ++ks) {
#pragma unroll
        for (int ct = 0; ct < 8; ++ct) {
            const int rr = ct * 16 + llo;
            bf16x8 bf = *(const bf16x8*)(Bs + rr * CH +
                                         ((ks * 4 + lhi) ^ (rr & 31)) * 8);
            acc[ct] = __builtin_amdgcn_mfma_f32_16x16x32_bf16(af[ks], bf, acc[ct], 0, 0, 0);
        }
    }

    u16* yn = y + (size_t)n * CH * LL;
#pragma unroll
    for (int r = 0; r < 4; ++r) {
        const int orow = o0 + w * 16 + lhi * 4 + r;
        float ts = 0.0f, tq = 0.0f;
#pragma unroll
        for (int ct = 0; ct < 8; ++ct) {
            float vv = acc[ct][r];
            yn[(size_t)orow * LL + l0 + ct * 16 + llo] = f2b(vv);
            ts += vv;
            tq += vv * vv;
        }
        ts += __shfl_xor(ts, 1); tq += __shfl_xor(tq, 1);
        ts += __shfl_xor(ts, 2); tq += __shfl_xor(tq, 2);
        ts += __shfl_xor(ts, 4); tq += __shfl_xor(tq, 4);
        ts += __shfl_xor(ts, 8); tq += __shfl_xor(tq, 8);
        if (llo == 0) {
            atomicAdd(&stats[orow], ts);
            atomicAdd(&stats[256 + orow], tq);
        }
    }
}

// ---------------------------------------------------------------------------
// Kernel 4: BN apply (batch stats, biased var) + residual. y read as bf16.
// ---------------------------------------------------------------------------
__global__ __launch_bounds__(256) void bn_kernel(
    const float* __restrict__ x, const u16* __restrict__ y,
    const float* __restrict__ stats, const float* __restrict__ gamma,
    const float* __restrict__ beta, float* __restrict__ out) {
    const int idx = blockIdx.x * 256 + threadIdx.x;  // per 4 elems
    const int base = idx * 4;
    const int c = (base >> 12) & 255;  // (base / L) % C
    const float cnt = 1.0f / 16384.0f; // N*L
    float mean = stats[c] * cnt;
    float var = stats[256 + c] * cnt - mean * mean;
    float rstd = rsqrtf(var + 1e-4f);
    float g = gamma[c] * rstd;
    float b = beta[c];
    uint2 yv = ((const uint2*)y)[idx];
    float4 xv = ((const float4*)x)[idx];
    float4 o;
    o.x = xv.x + (blo(yv.x) - mean) * g + b;
    o.y = xv.y + (bhi(yv.x) - mean) * g + b;
    o.z = xv.z + (blo(yv.y) - mean) * g + b;
    o.w = xv.w + (bhi(yv.y) - mean) * g + b;
    ((float4*)out)[idx] = o;
}

// ---------------------------------------------------------------------------
extern "C" void kernel_launch(void* const* d_in, const int* in_sizes, int n_in,
                              void* d_out, int out_size, void* d_ws, size_t ws_size,
                              hipStream_t stream) {
    const float* x = (const float*)d_in[0];
    const float* Wq = (const float*)d_in[1];
    const float* Wk = (const float*)d_in[2];
    const float* Wv = (const float*)d_in[3];
    const float* Wo = (const float*)d_in[4];
    const float* gamma = (const float*)d_in[5];
    const float* beta = (const float*)d_in[6];
    float* out = (float*)d_out;

    const size_t elems = (size_t)NB * LL * CH;  // 4,194,304

    // pick largest split count whose workspace fits (S=4 needs ~59.4 MB)
    int S = 1;
    for (int cand = 4; cand >= 2; cand >>= 1) {
        size_t need = elems * 2 * (size_t)(3 + cand) +
                      (size_t)cand * NB * LL * 4 + 524288 + 8192;
        if (ws_size >= need) { S = cand; break; }
    }
    const int iters = 128 / S;

    char* wsb = (char*)d_ws;
    u16* q = (u16*)wsb;                             // 8.39 MB (bf16)
    u16* k = q + elems;                             // 8.39 MB (bf16)
    u16* vT = k + elems;                            // 8.39 MB (bf16)
    u16* Op = vT + elems;                           // S * 8.39 MB (bf16)
    u16* xT = Op;                                   // overlay: dead before fattn
    float* l_s = (float*)(Op + (size_t)S * elems);  // S * 64 KB
    u16* Wb = (u16*)(l_s + (size_t)S * NB * LL);    // 512 KB
    float* stats = (float*)(Wb + 4 * 65536);        // 2 KB
    u16* att = q;   // overlay q (dead after fattn)
    u16* y = k;     // overlay k (dead after merge)

    prep_kernel<<<1280, 256, 0, stream>>>(x, Wq, Wk, Wv, Wo, Wb, stats, xT);
    proj_kernel<<<1536, 256, 0, stream>>>(xT, Wb, q, k, vT);
    fattn_kernel<<<dim3(LL / 128, NB, S), 256, 0, stream>>>(q, k, vT, Op, l_s, iters);
    merge_kernel<<<(int)(elems / 8 / 256), 256, 0, stream>>>(Op, l_s, att, S);
    outm_kernel<<<dim3(LL / 128, CH / 64, NB), 256, 0, stream>>>(Wb, att, y, stats);
    bn_kernel<<<(NB * CH * LL / 4) / 256, 256, 0, stream>>>(x, y, stats, gamma, beta, out);
}

// Round 9
// 197.439 us; speedup vs baseline: 2.9768x; 1.0319x over previous
//
#include <hip/hip_runtime.h>
#include <cstdint>
#include <cstddef>

// Problem constants: N=4, C=D=256, H=W=64, L=4096
#define NB 4
#define CH 256
#define LL 4096

typedef unsigned short u16;
typedef unsigned int u32;
typedef unsigned char u8;
typedef __attribute__((ext_vector_type(8))) short bf16x8;
typedef __attribute__((ext_vector_type(4))) float f32x4;
typedef __attribute__((ext_vector_type(16))) float f32x16;

#define GPTR(p) ((const __attribute__((address_space(1))) u32*)(p))
#define LPTR(p) ((__attribute__((address_space(3))) u32*)(p))

__device__ __forceinline__ float blo(u32 x) { return __uint_as_float(x << 16); }
__device__ __forceinline__ float bhi(u32 x) { return __uint_as_float(x & 0xffff0000u); }
__device__ __forceinline__ float b2f(u16 h) { return __uint_as_float(((u32)h) << 16); }
__device__ __forceinline__ u16 f2b(float f) {
    u32 u = __float_as_uint(f);
    u32 r = (u + 0x7fffu + ((u >> 16) & 1u)) >> 16;  // RNE
    return (u16)r;
}
__device__ __forceinline__ u32 pack2(float a, float b) {
    return (u32)f2b(a) | ((u32)f2b(b) << 16);
}

// ---------------------------------------------------------------------------
// Kernel P: fused castw + tcast (R16, kept).
// ids [0,1024): tcast 64x64 tile; ids [1024,1280): castw + stats zero.
// ---------------------------------------------------------------------------
__global__ __launch_bounds__(256) void prep_kernel(
    const float* __restrict__ x, const float* __restrict__ Wq,
    const float* __restrict__ Wk, const float* __restrict__ Wv,
    const float* __restrict__ Wo, u16* __restrict__ Wb,
    float* __restrict__ stats, u16* __restrict__ xT) {
    const int id = blockIdx.x;
    const int tid = threadIdx.x;
    __shared__ u16 t[64][72];
    if (id < 1024) {
        // ---- tcast: x[n][c][l] f32 -> xT[n][l][c] bf16 ----
        const int n = id >> 8;
        const int c0 = ((id >> 6) & 3) * 64, l0 = (id & 63) * 64;
        const float* xs = x + (size_t)n * CH * LL;
        const int lq = (tid & 15) * 4, cc = tid >> 4;
#pragma unroll
        for (int p = 0; p < 4; ++p) {
            int c = cc + p * 16;
            float4 v = *(const float4*)&xs[(size_t)(c0 + c) * LL + l0 + lq];
            t[lq + 0][c] = f2b(v.x);
            t[lq + 1][c] = f2b(v.y);
            t[lq + 2][c] = f2b(v.z);
            t[lq + 3][c] = f2b(v.w);
        }
        __syncthreads();
        u16* xo = xT + (size_t)n * LL * CH;
        const int l = tid >> 2, c8 = (tid & 3) * 16;
#pragma unroll
        for (int h = 0; h < 2; ++h) {
            uint4 vv = *(uint4*)&t[l][c8 + h * 8];
            *(uint4*)&xo[(size_t)(l0 + l) * CH + c0 + c8 + h * 8] = vv;
        }
    } else {
        // ---- castw: weights f32 -> bf16 Wb[mat][d][c]; zero BN stats ----
        const int j = id - 1024;
        const int i = (j & 63) * 256 + tid;
        const int m = j >> 6;
        if (m == 0 && (j & 63) < 2) stats[i] = 0.0f;
        const float* src = (m == 0) ? Wq : (m == 1) ? Wk : (m == 2) ? Wv : Wo;
        float4 v = ((const float4*)src)[i];
        uint2 o;
        o.x = pack2(v.x, v.y);
        o.y = pack2(v.z, v.w);
        ((uint2*)(Wb + m * 65536))[i] = o;
    }
}

// ---------------------------------------------------------------------------
// Kernel 1: fused projqk + projv (R16, kept). LDS-staged B-operand.
// ids [0,1024): q/k projection; ids [1024,1536): v projection.
// ---------------------------------------------------------------------------
__global__ __launch_bounds__(256, 2) void proj_kernel(
    const u16* __restrict__ xT, const u16* __restrict__ Wb,
    u16* __restrict__ q, u16* __restrict__ k, u16* __restrict__ vT) {
    const int id = blockIdx.x;
    const int tid = threadIdx.x;
    const int w = tid >> 6, lane = tid & 63;
    const int lhi = lane >> 4, llo = lane & 15;

    __shared__ __align__(16) u16 Bs[128 * 256];  // 64 KB, chunk-XOR swizzled

    if (id < 1024) {
        // ---- projqk ----
        const int n = id >> 8;
        const int yy = (id >> 6) & 3;
        const int dhalf = yy & 1, mat = yy >> 1;
        const int l0 = (id & 63) * 64;
        const int d0 = dhalf * 128;

        const u16* xn = xT + (size_t)n * LL * CH;
        const u16* Wm = Wb + mat * 65536 + (size_t)d0 * CH;

#pragma unroll
        for (int i = 0; i < 16; ++i) {
            int s = i * 256 + tid;
            int r = s >> 5, c = s & 31;
            __builtin_amdgcn_global_load_lds(GPTR(Wm + r * CH + (c ^ (r & 31)) * 8),
                                             LPTR((char*)Bs + i * 4096 + w * 1024),
                                             16, 0, 0);
        }

        bf16x8 af[8];
        const u16* abase = xn + (size_t)(l0 + w * 16 + llo) * CH + lhi * 8;
#pragma unroll
        for (int ks = 0; ks < 8; ++ks) af[ks] = *(const bf16x8*)(abase + ks * 32);

        f32x4 acc[8];
#pragma unroll
        for (int t = 0; t < 8; ++t) acc[t] = (f32x4){0.f, 0.f, 0.f, 0.f};

        __syncthreads();

#pragma unroll
        for (int ks = 0; ks < 8; ++ks) {
#pragma unroll
            for (int ct = 0; ct < 8; ++ct) {
                const int rr = ct * 16 + llo;
                bf16x8 bf = *(const bf16x8*)(Bs + rr * CH +
                                             ((ks * 4 + lhi) ^ (rr & 31)) * 8);
                acc[ct] = __builtin_amdgcn_mfma_f32_16x16x32_bf16(af[ks], bf, acc[ct], 0, 0, 0);
            }
        }

        u16* o = (mat ? k : q) + (size_t)n * LL * CH;
#pragma unroll
        for (int r = 0; r < 4; ++r) {
            int lr = l0 + w * 16 + lhi * 4 + r;
#pragma unroll
            for (int ct = 0; ct < 8; ++ct)
                o[(size_t)lr * CH + d0 + ct * 16 + llo] = f2b(acc[ct][r]);
        }
    } else {
        // ---- projv ----
        const int j = id - 1024;
        const int n = j >> 7;
        const int d0 = ((j >> 5) & 3) * 64;
        const int l0 = (j & 31) * 128;

        const u16* xn = xT + (size_t)n * LL * CH + (size_t)l0 * CH;
        const u16* Wm = Wb + 2 * 65536;

#pragma unroll
        for (int i = 0; i < 16; ++i) {
            int s = i * 256 + tid;
            int r = s >> 5, c = s & 31;
            __builtin_amdgcn_global_load_lds(GPTR(xn + r * CH + (c ^ (r & 31)) * 8),
                                             LPTR((char*)Bs + i * 4096 + w * 1024),
                                             16, 0, 0);
        }

        bf16x8 af[8];
        const u16* abase = Wm + (size_t)(d0 + w * 16 + llo) * CH + lhi * 8;
#pragma unroll
        for (int ks = 0; ks < 8; ++ks) af[ks] = *(const bf16x8*)(abase + ks * 32);

        f32x4 acc[8];
#pragma unroll
        for (int t = 0; t < 8; ++t) acc[t] = (f32x4){0.f, 0.f, 0.f, 0.f};

        __syncthreads();

#pragma unroll
        for (int ks = 0; ks < 8; ++ks) {
#pragma unroll
            for (int ct = 0; ct < 8; ++ct) {
                const int rr = ct * 16 + llo;
                bf16x8 bf = *(const bf16x8*)(Bs + rr * CH +
                                             ((ks * 4 + lhi) ^ (rr & 31)) * 8);
                acc[ct] = __builtin_amdgcn_mfma_f32_16x16x32_bf16(af[ks], bf, acc[ct], 0, 0, 0);
            }
        }

        u16* o = vT + (size_t)n * CH * LL;
#pragma unroll
        for (int r = 0; r < 4; ++r) {
            int dr = d0 + w * 16 + lhi * 4 + r;
#pragma unroll
            for (int ct = 0; ct < 8; ++ct)
                o[(size_t)dr * LL + l0 + ct * 16 + llo] = f2b(acc[ct][r]);
        }
    }
}

// ---------------------------------------------------------------------------
// Kernel 2: bf16 flash attention (R19 = R18 with the permlane fix).
// R8 post-mortem: absmax 9.2 -- the v_permlane32_swap operand roles were
// mirrored. True CDNA4 semantics: "exchange DST.row[1] with SRC0.row[0]",
// i.e. new vdst = {old vdst.lo32, old vsrc.lo32}, new vsrc = {old vdst.hi32,
// old vsrc.hi32}. Required P->A-frag mapping (lane (q=l31,h), k-step sp,
// word j = k{16sp+8h+2j,+1}): word j = new vdst, word 2+j = new vsrc of
// swap(vdst=W[2sp][j], vsrc=W[2sp+1][j]). R8 had the pair reversed ->
// wrong-half wrong-g data. All other derivations re-verified by example:
// K A-frag chunk (2s^h)^l31, Q B-frag, S^T C-layout (row=k,col=q), V B-frag
// chunk 2sp^hg, O row map (r&3)+8(r>>2)+4h, lrun xor-32 reduce.
// Structure: QK^T = one 32x32x16 chain (16 c-steps); PV = 8 d-tiles x 2
// k-steps; 16 ds_bpermute -> 4 permlane32_swap (VALU). LDS 65536, 2 blk/CU.
// ---------------------------------------------------------------------------
__global__ __launch_bounds__(256, 2) void fattn_kernel(
    const u16* __restrict__ q, const u16* __restrict__ k,
    const u16* __restrict__ vT, u16* __restrict__ Op, float* __restrict__ l_s,
    int iters) {
    const int n = blockIdx.y;
    const int s_id = blockIdx.z;
    const int l0 = blockIdx.x * 128;
    const int m_base = s_id * iters * 32;
    const int tid = threadIdx.x;
    const int w = tid >> 6;
    const int lane = tid & 63;
    const int l31 = lane & 31;
    const int h = lane >> 5;

    __shared__ __align__(16) char smem[65536];
    // K buffers @ 0 / 16384 ; V buffers @ 32768 / 49152

    // ---- Q fragments: lane holds Q[q=w*32+l31][c = s*16 + h*8 .. +8] ----
    bf16x8 qf[16];
    {
        const u16* base = q + (size_t)(n * LL + l0 + w * 32 + l31) * CH + h * 8;
#pragma unroll
        for (int s = 0; s < 16; ++s) qf[s] = *(const bf16x8*)(base + s * 16);
    }

    const u16* kg = k + (size_t)n * LL * CH;
    const u16* vg = vT + (size_t)n * CH * LL;

    // iter-invariant swizzled staging offsets (u16 elems); slot s = i*256+tid
    int okK[4], okV[4];
#pragma unroll
    for (int i = 0; i < 4; ++i) {
        int s = i * 256 + tid;
        int rK = s >> 5;
        int cK = (s & 31) ^ rK;
        okK[i] = rK * CH + cK * 8;
        int dV = s >> 2;
        int cV = (s & 3) ^ ((dV & 3) ^ ((dV >> 2) & 3));
        okV[i] = dV * LL + cV * 8;
    }

    f32x16 oacc[8];
#pragma unroll
    for (int t = 0; t < 8; ++t)
        oacc[t] = (f32x16){0.f, 0.f, 0.f, 0.f, 0.f, 0.f, 0.f, 0.f,
                           0.f, 0.f, 0.f, 0.f, 0.f, 0.f, 0.f, 0.f};
    float lrun = 0.f;

    const float C1 = 0.09016844005556021f;  // (1/16) * log2(e)
    const int kx = h ^ l31;                              // K read chunk XOR
    const int hg = h ^ ((lane & 3) ^ ((lane >> 2) & 3)); // V read chunk base

    // ---- prologue: issue tile 0 into buffer 0 ----
    {
        const u16* kg2 = kg + (size_t)m_base * CH;
        const u16* vg2 = vg + m_base;
#pragma unroll
        for (int i = 0; i < 4; ++i) {
            __builtin_amdgcn_global_load_lds(GPTR(kg2 + okK[i]),
                                             LPTR(smem + i * 4096 + w * 1024), 16, 0, 0);
            __builtin_amdgcn_global_load_lds(GPTR(vg2 + okV[i]),
                                             LPTR(smem + 32768 + i * 4096 + w * 1024),
                                             16, 0, 0);
        }
    }

    for (int it = 0; it < iters; ++it) {
        __syncthreads();
        if (it + 1 < iters) {
            const int m1 = m_base + (it + 1) * 32;
            const u16* kg2 = kg + (size_t)m1 * CH;
            const u16* vg2 = vg + m1;
            char* Kb = smem + ((it + 1) & 1) * 16384;
            char* Vb = smem + 32768 + ((it + 1) & 1) * 16384;
#pragma unroll
            for (int i = 0; i < 4; ++i) {
                __builtin_amdgcn_global_load_lds(GPTR(kg2 + okK[i]),
                                                 LPTR(Kb + i * 4096 + w * 1024), 16, 0, 0);
                __builtin_amdgcn_global_load_lds(GPTR(vg2 + okV[i]),
                                                 LPTR(Vb + i * 4096 + w * 1024), 16, 0, 0);
            }
        }
        const u16* Kl = (const u16*)(smem + (it & 1) * 16384);
        const u16* Vl = (const u16*)(smem + 32768 + (it & 1) * 16384);

        // ---- S^T = K*Q^T as one 32x32x16 chain over 16 c-steps.
        // A-frag: K[row=l31][c = s*16 + h*8 ..], stored chunk XOR'd by row. ----
        f32x16 sacc = (f32x16){0.f, 0.f, 0.f, 0.f, 0.f, 0.f, 0.f, 0.f,
                               0.f, 0.f, 0.f, 0.f, 0.f, 0.f, 0.f, 0.f};
        __builtin_amdgcn_s_setprio(1);
#pragma unroll
        for (int s = 0; s < 16; ++s) {
            bf16x8 af = *(const bf16x8*)(Kl + l31 * 256 + ((2 * s) ^ kx) * 8);
            sacc = __builtin_amdgcn_mfma_f32_32x32x16_bf16(af, qf[s], sacc, 0, 0, 0);
        }
        __builtin_amdgcn_s_setprio(0);

        // ---- softmax: lane holds S[k = (r&3)+8*(r>>2)+4h][q = l31].
        // p = exp2(s*C1); pack pairs W[g][j] (g = r>>2); lrun += sum. ----
        u32 W[4][2];
#pragma unroll
        for (int g = 0; g < 4; ++g) {
            float p0 = __builtin_amdgcn_exp2f(sacc[4 * g + 0] * C1);
            float p1 = __builtin_amdgcn_exp2f(sacc[4 * g + 1] * C1);
            float p2 = __builtin_amdgcn_exp2f(sacc[4 * g + 2] * C1);
            float p3 = __builtin_amdgcn_exp2f(sacc[4 * g + 3] * C1);
            lrun += (p0 + p1) + (p2 + p3);
            asm("v_cvt_pk_bf16_f32 %0, %1, %2" : "=v"(W[g][0]) : "v"(p0), "v"(p1));
            asm("v_cvt_pk_bf16_f32 %0, %1, %2" : "=v"(W[g][1]) : "v"(p2), "v"(p3));
        }

        // ---- P->A-frags via permlane32_swap. Semantics: new vdst =
        // {old vdst.lo, old vsrc.lo}; new vsrc = {old vdst.hi, old vsrc.hi}.
        // swap(vdst=W[2sp][j], vsrc=W[2sp+1][j]): word j = vdst, 2+j = vsrc. ----
        bf16x8 pa[2];
#pragma unroll
        for (int sp = 0; sp < 2; ++sp) {
            u32 a0 = W[2 * sp][0], b0 = W[2 * sp + 1][0];
            asm("v_permlane32_swap_b32 %0, %1" : "+v"(a0), "+v"(b0));
            u32 a1 = W[2 * sp][1], b1 = W[2 * sp + 1][1];
            asm("v_permlane32_swap_b32 %0, %1" : "+v"(a1), "+v"(b1));
            union { u32 u[4]; bf16x8 v; } pk;
            pk.u[0] = a0;
            pk.u[1] = a1;
            pk.u[2] = b0;
            pk.u[3] = b1;
            pa[sp] = pk.v;
        }

        // ---- PV: O[q][d], 8 d-tiles x 2 k-steps of 32x32x16.
        // B-frag: V^T[d = dt*32 + l31][k = sp*16 + h*8 ..], chunk-XOR read. ----
        __builtin_amdgcn_s_setprio(1);
#pragma unroll
        for (int sp = 0; sp < 2; ++sp) {
#pragma unroll
            for (int dt = 0; dt < 8; ++dt) {
                bf16x8 vf = *(const bf16x8*)(Vl + (dt * 32 + l31) * 32 +
                                             ((2 * sp) ^ hg) * 8);
                oacc[dt] = __builtin_amdgcn_mfma_f32_32x32x16_bf16(pa[sp], vf, oacc[dt], 0, 0, 0);
            }
        }
        __builtin_amdgcn_s_setprio(0);
    }

    // ---- epilogue: store un-normalized partial O (bf16) + l (fp32).
    // oacc[dt][r] = O[q = (r&3)+8*(r>>2)+4h][d = dt*32 + l31]. ----
    u16* ap = Op + (size_t)((s_id * NB + n) * (size_t)LL + l0 + w * 32) * CH;
    float* lp = l_s + (size_t)s_id * NB * LL + (size_t)n * LL + l0 + w * 32;
    lrun += __shfl_xor(lrun, 32);
    if (h == 0) lp[l31] = lrun;
#pragma unroll
    for (int dt = 0; dt < 8; ++dt) {
#pragma unroll
        for (int r = 0; r < 16; ++r) {
            int qrow = (r & 3) + 8 * (r >> 2) + 4 * h;
            ap[(size_t)qrow * CH + dt * 32 + l31] = f2b(oacc[dt][r]);
        }
    }
}

// ---------------------------------------------------------------------------
// Kernel 2c: merge splits: att[i] = (sum_s Op[s][i]) / (sum_s l_s[s][row])
// ---------------------------------------------------------------------------
__global__ __launch_bounds__(256) void merge_kernel(
    const u16* __restrict__ Op, const float* __restrict__ l_s,
    u16* __restrict__ att, int S) {
    const size_t t8 = (size_t)blockIdx.x * 256 + threadIdx.x;
    const size_t flat = t8 * 8;
    const size_t row = flat >> 8;
    float lsum = 0.0f;
    for (int s = 0; s < S; ++s) lsum += l_s[(size_t)s * NB * LL + row];
    const float inv = 1.0f / lsum;
    float acc[8];
#pragma unroll
    for (int j = 0; j < 8; ++j) acc[j] = 0.0f;
    for (int s = 0; s < S; ++s) {
        uint4 raw = *(const uint4*)(Op + (size_t)s * NB * LL * CH + flat);
        acc[0] += blo(raw.x); acc[1] += bhi(raw.x);
        acc[2] += blo(raw.y); acc[3] += bhi(raw.y);
        acc[4] += blo(raw.z); acc[5] += bhi(raw.z);
        acc[6] += blo(raw.w); acc[7] += bhi(raw.w);
    }
    uint4 o;
    o.x = pack2(acc[0] * inv, acc[1] * inv);
    o.y = pack2(acc[2] * inv, acc[3] * inv);
    o.z = pack2(acc[4] * inv, acc[5] * inv);
    o.w = pack2(acc[6] * inv, acc[7] * inv);
    *(uint4*)(att + flat) = o;
}

// ---------------------------------------------------------------------------
// Kernel 3: output projection via MFMA + fused BN partial sums. y bf16.
// B = att l-tile staged in LDS (R14 template).
// ---------------------------------------------------------------------------
__global__ __launch_bounds__(256, 2) void outm_kernel(
    const u16* __restrict__ Wb, const u16* __restrict__ att,
    u16* __restrict__ y, float* __restrict__ stats) {
    const int n = blockIdx.z;
    const int o0 = blockIdx.y * 64;
    const int l0 = blockIdx.x * 128;
    const int tid = threadIdx.x;
    const int w = tid >> 6, lane = tid & 63;
    const int lhi = lane >> 4, llo = lane & 15;

    __shared__ __align__(16) u16 Bs[128 * 256];  // 64 KB

    const u16* an = att + (size_t)n * LL * CH + (size_t)l0 * CH;
    const u16* Wm = Wb + 3 * 65536;

#pragma unroll
    for (int i = 0; i < 16; ++i) {
        int s = i * 256 + tid;
        int r = s >> 5, c = s & 31;
        __builtin_amdgcn_global_load_lds(GPTR(an + r * CH + (c ^ (r & 31)) * 8),
                                         LPTR((char*)Bs + i * 4096 + w * 1024),
                                         16, 0, 0);
    }

    bf16x8 af[8];
    const u16* abase = Wm + (size_t)(o0 + w * 16 + llo) * CH + lhi * 8;
#pragma unroll
    for (int ks = 0; ks < 8; ++ks) af[ks] = *(const bf16x8*)(abase + ks * 32);

    f32x4 acc[8];
#pragma unroll
    for (int t = 0; t < 8; ++t) acc[t] = (f32x4){0.f, 0.f, 0.f, 0.f};

    __syncthreads();

#pragma unroll
    for (int ks = 0; ks < 8; ++ks) {
#pragma unroll
        for (int ct = 0; ct < 8; ++ct) {
            const int rr = ct * 16 + llo;
            bf16x8 bf = *(const bf16x8*)(Bs + rr * CH +
                                         ((ks * 4 + lhi) ^ (rr & 31)) * 8);
            acc[ct] = __builtin_amdgcn_mfma_f32_16x16x32_bf16(af[ks], bf, acc[ct], 0, 0, 0);
        }
    }

    u16* yn = y + (size_t)n * CH * LL;
#pragma unroll
    for (int r = 0; r < 4; ++r) {
        const int orow = o0 + w * 16 + lhi * 4 + r;
        float ts = 0.0f, tq = 0.0f;
#pragma unroll
        for (int ct = 0; ct < 8; ++ct) {
            float vv = acc[ct][r];
            yn[(size_t)orow * LL + l0 + ct * 16 + llo] = f2b(vv);
            ts += vv;
            tq += vv * vv;
        }
        ts += __shfl_xor(ts, 1); tq += __shfl_xor(tq, 1);
        ts += __shfl_xor(ts, 2); tq += __shfl_xor(tq, 2);
        ts += __shfl_xor(ts, 4); tq += __shfl_xor(tq, 4);
        ts += __shfl_xor(ts, 8); tq += __shfl_xor(tq, 8);
        if (llo == 0) {
            atomicAdd(&stats[orow], ts);
            atomicAdd(&stats[256 + orow], tq);
        }
    }
}

// ---------------------------------------------------------------------------
// Kernel 4: BN apply (batch stats, biased var) + residual. y read as bf16.
// ---------------------------------------------------------------------------
__global__ __launch_bounds__(256) void bn_kernel(
    const float* __restrict__ x, const u16* __restrict__ y,
    const float* __restrict__ stats, const float* __restrict__ gamma,
    const float* __restrict__ beta, float* __restrict__ out) {
    const int idx = blockIdx.x * 256 + threadIdx.x;  // per 4 elems
    const int base = idx * 4;
    const int c = (base >> 12) & 255;  // (base / L) % C
    const float cnt = 1.0f / 16384.0f; // N*L
    float mean = stats[c] * cnt;
    float var = stats[256 + c] * cnt - mean * mean;
    float rstd = rsqrtf(var + 1e-4f);
    float g = gamma[c] * rstd;
    float b = beta[c];
    uint2 yv = ((const uint2*)y)[idx];
    float4 xv = ((const float4*)x)[idx];
    float4 o;
    o.x = xv.x + (blo(yv.x) - mean) * g + b;
    o.y = xv.y + (bhi(yv.x) - mean) * g + b;
    o.z = xv.z + (blo(yv.y) - mean) * g + b;
    o.w = xv.w + (bhi(yv.y) - mean) * g + b;
    ((float4*)out)[idx] = o;
}

// ---------------------------------------------------------------------------
extern "C" void kernel_launch(void* const* d_in, const int* in_sizes, int n_in,
                              void* d_out, int out_size, void* d_ws, size_t ws_size,
                              hipStream_t stream) {
    const float* x = (const float*)d_in[0];
    const float* Wq = (const float*)d_in[1];
    const float* Wk = (const float*)d_in[2];
    const float* Wv = (const float*)d_in[3];
    const float* Wo = (const float*)d_in[4];
    const float* gamma = (const float*)d_in[5];
    const float* beta = (const float*)d_in[6];
    float* out = (float*)d_out;

    const size_t elems = (size_t)NB * LL * CH;  // 4,194,304

    // pick largest split count whose workspace fits (S=4 needs ~59.4 MB)
    int S = 1;
    for (int cand = 4; cand >= 2; cand >>= 1) {
        size_t need = elems * 2 * (size_t)(3 + cand) +
                      (size_t)cand * NB * LL * 4 + 524288 + 8192;
        if (ws_size >= need) { S = cand; break; }
    }
    const int iters = 128 / S;

    char* wsb = (char*)d_ws;
    u16* q = (u16*)wsb;                             // 8.39 MB (bf16)
    u16* k = q + elems;                             // 8.39 MB (bf16)
    u16* vT = k + elems;                            // 8.39 MB (bf16)
    u16* Op = vT + elems;                           // S * 8.39 MB (bf16)
    u16* xT = Op;                                   // overlay: dead before fattn
    float* l_s = (float*)(Op + (size_t)S * elems);  // S * 64 KB
    u16* Wb = (u16*)(l_s + (size_t)S * NB * LL);    // 512 KB
    float* stats = (float*)(Wb + 4 * 65536);        // 2 KB
    u16* att = q;   // overlay q (dead after fattn)
    u16* y = k;     // overlay k (dead after merge)

    prep_kernel<<<1280, 256, 0, stream>>>(x, Wq, Wk, Wv, Wo, Wb, stats, xT);
    proj_kernel<<<1536, 256, 0, stream>>>(xT, Wb, q, k, vT);
    fattn_kernel<<<dim3(LL / 128, NB, S), 256, 0, stream>>>(q, k, vT, Op, l_s, iters);
    merge_kernel<<<(int)(elems / 8 / 256), 256, 0, stream>>>(Op, l_s, att, S);
    outm_kernel<<<dim3(LL / 128, CH / 64, NB), 256, 0, stream>>>(Wb, att, y, stats);
    bn_kernel<<<(NB * CH * LL / 4) / 256, 256, 0, stream>>>(x, y, stats, gamma, beta, out);
}